// Round 5
// baseline (2571.041 us; speedup 1.0000x reference)
//
#include <hip/hip_runtime.h>
#include <cstdint>

#define B_SZ 2048
#define SEQ  16
#define DIM  1024
#define HID  512
#define DK   512
#define NH   4
#define DH   128
#define GATE 2048
#define EPSV 1e-5f
#define RROWS 16

typedef __bf16 bf8_t __attribute__((ext_vector_type(8)));
typedef float  f4_t  __attribute__((ext_vector_type(4)));
typedef unsigned short u16x8 __attribute__((ext_vector_type(8)));
typedef unsigned short u16x4 __attribute__((ext_vector_type(4)));

__device__ __forceinline__ unsigned short f2bf(float f){
  __bf16 h = (__bf16)f;                       // RNE
  return __builtin_bit_cast(unsigned short, h);
}
__device__ __forceinline__ float bf2f(unsigned short u){
  return __builtin_bit_cast(float, ((unsigned int)u) << 16);
}
__device__ __forceinline__ float sigm(float x){ return 1.f/(1.f+__expf(-x)); }
__device__ __forceinline__ float tanh_f(float x){ return 1.f - 2.f/(__expf(2.f*x)+1.f); }

__device__ __forceinline__ void gload16(const void* g, void* l){
  __builtin_amdgcn_global_load_lds(
      (const __attribute__((address_space(1))) void*)g,
      (__attribute__((address_space(3))) void*)l, 16, 0, 0);
}

// ------------- bf16 BT GEMM 128x128 (m97 structure + granule-XOR swizzle; r3-proven) -------------
template<bool OUT_BF16, bool BIAS, bool RELU>
__global__ __launch_bounds__(256) void gemm16(
    const unsigned short* __restrict__ A,
    const unsigned short* __restrict__ Bw,
    const float* __restrict__ bias,
    void* __restrict__ Cp,
    int N, int K, int nwg)
{
  __shared__ __align__(16) unsigned short As[128*64];
  __shared__ __align__(16) unsigned short Bs[128*64];
  const int tid = threadIdx.x, lane = tid & 63, wave = tid >> 6;
  const int bid = blockIdx.x;
  const int swz = (bid & 7)*(nwg >> 3) + (bid >> 3);   // nwg % 8 == 0 at all call sites
  const int nx  = N >> 7;
  const int lnx = 31 - __clz(nx);
  const int bm0 = (swz >> lnx) << 7;
  const int bn0 = (swz & (nx-1)) << 7;

  const int r8  = lane >> 3;
  const int gsw = ((lane & 7) ^ r8) * 8;     // pre-swizzled source granule
  const unsigned short* Ab = A  + (size_t)(bm0 + wave*32 + r8)*K + gsw;
  const unsigned short* Bb = Bw + (size_t)(bn0 + wave*32 + r8)*K + gsw;
  unsigned short* la = As + wave*2048;
  unsigned short* lb = Bs + wave*2048;

  f4_t acc[4][4];
  #pragma unroll
  for (int m=0;m<4;++m)
    #pragma unroll
    for (int n=0;n<4;++n) acc[m][n] = (f4_t)0.f;

  const int KT = K >> 6;
  const int fr = lane & 15, kg = lane >> 4;
  const int wm = (wave & 1)*64, wn = (wave >> 1)*64;

  for (int kt = 0; kt < KT; ++kt){
    if (kt) __syncthreads();
    const size_t ko = (size_t)kt*64;
    #pragma unroll
    for (int q = 0; q < 4; ++q){
      gload16(Ab + ko + (size_t)q*8*K, la + q*512);
      gload16(Bb + ko + (size_t)q*8*K, lb + q*512);
    }
    __syncthreads();
    #pragma unroll
    for (int kk = 0; kk < 2; ++kk){
      bf8_t af[4], bf_[4];
      #pragma unroll
      for (int m=0;m<4;++m){
        const int r = wm+m*16+fr;
        af[m]  = *(const bf8_t*)&As[r*64 + (((kk*4+kg) ^ (r&7))*8)];
      }
      #pragma unroll
      for (int n=0;n<4;++n){
        const int r = wn+n*16+fr;
        bf_[n] = *(const bf8_t*)&Bs[r*64 + (((kk*4+kg) ^ (r&7))*8)];
      }
      #pragma unroll
      for (int m=0;m<4;++m)
        #pragma unroll
        for (int n=0;n<4;++n)
          acc[m][n] = __builtin_amdgcn_mfma_f32_16x16x32_bf16(af[m], bf_[n], acc[m][n], 0,0,0);
    }
  }

  #pragma unroll
  for (int n=0;n<4;++n){
    const int col = bn0 + wn + n*16 + fr;
    float bv = 0.f;
    if constexpr (BIAS) bv = bias[col];
    #pragma unroll
    for (int m=0;m<4;++m){
      #pragma unroll
      for (int j=0;j<4;++j){
        const int row = bm0 + wm + m*16 + kg*4 + j;
        float v = acc[m][n][j] + bv;
        if constexpr (RELU) v = fmaxf(v, 0.f);
        if constexpr (OUT_BF16) ((unsigned short*)Cp)[(size_t)row*N + col] = f2bf(v);
        else                    ((float*)Cp)[(size_t)row*N + col] = v;
      }
    }
  }
}

// ------------- GEMM1 with fused fp32->bf16 A conversion -------------
// A from 4 fp32 sources (1024 cols each, concat K=4096), reg-staged + cvt + swizzled ds_write.
// B via gload16 (linear dest, pre-swizzled source). Counted vmcnt(8) keeps the next-tile
// A-f32 prefetch in flight across the barrier; sched_barrier(0) pins issue order so the
// 4 oldest VMEM ops at the waitcnt are exactly this tile's B gloads.
__global__ __launch_bounds__(256) void gemm16f(
    const float* __restrict__ A0, const float* __restrict__ A1,
    const float* __restrict__ A2, const float* __restrict__ A3,
    const unsigned short* __restrict__ Bw,
    const float* __restrict__ bias,
    unsigned short* __restrict__ Cp,
    int N, int K, int nwg)
{
  __shared__ __align__(16) unsigned short As[128*64];
  __shared__ __align__(16) unsigned short Bs[128*64];
  const int tid = threadIdx.x, lane = tid & 63, wave = tid >> 6;
  const int bid = blockIdx.x;
  const int swz = (bid & 7)*(nwg >> 3) + (bid >> 3);
  const int nx  = N >> 7;
  const int lnx = 31 - __clz(nx);
  const int bm0 = (swz >> lnx) << 7;
  const int bn0 = (swz & (nx-1)) << 7;

  const int r8  = lane >> 3;
  const int gsw = ((lane & 7) ^ r8) * 8;
  const unsigned short* Bb = Bw + (size_t)(bn0 + wave*32 + r8)*K + gsw;
  unsigned short* lb = Bs + wave*2048;

  const int arow = tid >> 3, acolg = tid & 7;   // A staging: rows q*32+arow, granule acolg
  f4_t ra[4][2];

  auto loadA = [&](int kt){
    const int kbase = kt*64;
    const int src = kbase >> 10;
    const int kc  = kbase & 1023;
    const float* Asel = src==0?A0 : src==1?A1 : src==2?A2 : A3;
    #pragma unroll
    for (int q=0;q<4;++q){
      const float* p = Asel + (size_t)(bm0 + q*32 + arow)*1024 + kc + acolg*8;
      ra[q][0] = *(const f4_t*)p;
      ra[q][1] = *(const f4_t*)(p+4);
    }
  };
  auto storeA = [&](){
    #pragma unroll
    for (int q=0;q<4;++q){
      const int row = q*32 + arow;
      u16x8 wv;
      #pragma unroll
      for (int j=0;j<4;++j){ wv[j]=f2bf(ra[q][0][j]); wv[4+j]=f2bf(ra[q][1][j]); }
      *(u16x8*)&As[row*64 + ((acolg ^ (row&7))*8)] = wv;   // swizzled dest (ds_write+ds_read pair)
    }
  };

  f4_t acc[4][4];
  #pragma unroll
  for (int m=0;m<4;++m)
    #pragma unroll
    for (int n=0;n<4;++n) acc[m][n] = (f4_t)0.f;

  const int KT = K >> 6;
  const int fr = lane & 15, kg = lane >> 4;
  const int wm = (wave & 1)*64, wn = (wave >> 1)*64;

  loadA(0);
  for (int kt = 0; kt < KT; ++kt){
    if (kt) __builtin_amdgcn_s_barrier();       // all waves done reading LDS tile kt-1
    storeA();                                    // consumes ra (compiler waits their vmcnt)
    const size_t ko = (size_t)kt*64;
    #pragma unroll
    for (int q = 0; q < 4; ++q) gload16(Bb + ko + (size_t)q*8*K, lb + q*512);
    __builtin_amdgcn_sched_barrier(0);           // pin: B gloads issued before A-next loads
    if (kt+1 < KT){
      loadA(kt+1);                               // 8 f32 loads, stay in flight across barrier
      __builtin_amdgcn_sched_barrier(0);
      asm volatile("s_waitcnt vmcnt(8)" ::: "memory");   // drains the 4 B gloads (oldest)
    } else {
      asm volatile("s_waitcnt vmcnt(0)" ::: "memory");
    }
    asm volatile("s_waitcnt lgkmcnt(0)" ::: "memory");   // own ds_writes visible
    __builtin_amdgcn_s_barrier();
    __builtin_amdgcn_sched_barrier(0);           // rule-18 fence
    #pragma unroll
    for (int kk = 0; kk < 2; ++kk){
      bf8_t af[4], bf_[4];
      #pragma unroll
      for (int m=0;m<4;++m){
        const int r = wm+m*16+fr;
        af[m]  = *(const bf8_t*)&As[r*64 + (((kk*4+kg) ^ (r&7))*8)];
      }
      #pragma unroll
      for (int n=0;n<4;++n){
        const int r = wn+n*16+fr;
        bf_[n] = *(const bf8_t*)&Bs[r*64 + (((kk*4+kg) ^ (r&7))*8)];
      }
      #pragma unroll
      for (int m=0;m<4;++m)
        #pragma unroll
        for (int n=0;n<4;++n)
          acc[m][n] = __builtin_amdgcn_mfma_f32_16x16x32_bf16(af[m], bf_[n], acc[m][n], 0,0,0);
    }
  }

  #pragma unroll
  for (int n=0;n<4;++n){
    const int col = bn0 + wn + n*16 + fr;
    const float bv = bias[col];
    #pragma unroll
    for (int m=0;m<4;++m){
      #pragma unroll
      for (int j=0;j<4;++j){
        const int row = bm0 + wm + m*16 + kg*4 + j;
        float v = fmaxf(acc[m][n][j] + bv, 0.f);
        Cp[(size_t)row*N + col] = f2bf(v);
      }
    }
  }
}

// ------------- bf16 BT GEMM 64x64 (for the small q GEMM) -------------
template<bool OUT_BF16, bool BIAS>
__global__ __launch_bounds__(256) void gemm64(
    const unsigned short* __restrict__ A,
    const unsigned short* __restrict__ Bw,
    const float* __restrict__ bias,
    void* __restrict__ Cp,
    int N, int K, int nwg)
{
  __shared__ __align__(16) unsigned short As[64*64];
  __shared__ __align__(16) unsigned short Bs[64*64];
  const int tid = threadIdx.x, lane = tid & 63, wave = tid >> 6;
  const int bid = blockIdx.x;
  const int swz = (bid & 7)*(nwg >> 3) + (bid >> 3);
  const int nx  = N >> 6;
  const int lnx = 31 - __clz(nx);
  const int bm0 = (swz >> lnx) << 6;
  const int bn0 = (swz & (nx-1)) << 6;

  const int r8  = lane >> 3;
  const int gsw = ((lane & 7) ^ r8) * 8;
  const unsigned short* Ab = A  + (size_t)(bm0 + wave*16 + r8)*K + gsw;
  const unsigned short* Bb = Bw + (size_t)(bn0 + wave*16 + r8)*K + gsw;
  unsigned short* la = As + wave*1024;
  unsigned short* lb = Bs + wave*1024;

  f4_t acc[2][2];
  #pragma unroll
  for (int m=0;m<2;++m)
    #pragma unroll
    for (int n=0;n<2;++n) acc[m][n] = (f4_t)0.f;

  const int KT = K >> 6;
  const int fr = lane & 15, kg = lane >> 4;
  const int wm = (wave & 1)*32, wn = (wave >> 1)*32;

  for (int kt = 0; kt < KT; ++kt){
    if (kt) __syncthreads();
    const size_t ko = (size_t)kt*64;
    #pragma unroll
    for (int q = 0; q < 2; ++q){
      gload16(Ab + ko + (size_t)q*8*K, la + q*512);
      gload16(Bb + ko + (size_t)q*8*K, lb + q*512);
    }
    __syncthreads();
    #pragma unroll
    for (int kk = 0; kk < 2; ++kk){
      bf8_t af[2], bf_[2];
      #pragma unroll
      for (int m=0;m<2;++m){
        const int r = wm+m*16+fr;
        af[m]  = *(const bf8_t*)&As[r*64 + (((kk*4+kg) ^ (r&7))*8)];
      }
      #pragma unroll
      for (int n=0;n<2;++n){
        const int r = wn+n*16+fr;
        bf_[n] = *(const bf8_t*)&Bs[r*64 + (((kk*4+kg) ^ (r&7))*8)];
      }
      #pragma unroll
      for (int m=0;m<2;++m)
        #pragma unroll
        for (int n=0;n<2;++n)
          acc[m][n] = __builtin_amdgcn_mfma_f32_16x16x32_bf16(af[m], bf_[n], acc[m][n], 0,0,0);
    }
  }

  #pragma unroll
  for (int n=0;n<2;++n){
    const int col = bn0 + wn + n*16 + fr;
    float bv = 0.f;
    if constexpr (BIAS) bv = bias[col];
    #pragma unroll
    for (int m=0;m<2;++m){
      #pragma unroll
      for (int j=0;j<4;++j){
        const int row = bm0 + wm + m*16 + kg*4 + j;
        float v = acc[m][n][j] + bv;
        if constexpr (OUT_BF16) ((unsigned short*)Cp)[(size_t)row*N + col] = f2bf(v);
        else                    ((float*)Cp)[(size_t)row*N + col] = v;
      }
    }
  }
}

// ============ fused 16-step LSTM recurrence (row-independent across batch) ============
// 128 WGs x 512 threads; WG owns 16 batch rows. h: LDS bf16 (XOR-swizzled, MFMA A-operand);
// c: registers f32 (16/thread); gates_h: LDS f32 (granule-swizzled); Whh streamed from L2.
__global__ __launch_bounds__(512) void rec_fused(
  const unsigned short* __restrict__ X,      // [B*SEQ][2048] bf16
  const unsigned short* __restrict__ Whhb,   // [2048][512] bf16
  const float* __restrict__ h0, const float* __restrict__ c0,
  const float* __restrict__ g_ih, const float* __restrict__ b_ih,
  const float* __restrict__ g_hh, const float* __restrict__ b_hh,
  const float* __restrict__ g_c,  const float* __restrict__ b_c,
  unsigned short* __restrict__ lo,           // [B*SEQ][512] bf16
  unsigned short* __restrict__ hb)           // [B][512] bf16 (t=15)
{
  __shared__ float gates[RROWS*2048];            // 128 KB, f32, granule-swizzled
  __shared__ unsigned short hsh[RROWS*512];      // 16 KB, bf16, granule-swizzled
  __shared__ float part[8][RROWS][2];
  __shared__ float stats[RROWS][4];              // mH,rH,mX,rX
  const int tid = threadIdx.x, lane = tid & 63, w = tid >> 6;
  const int r0  = blockIdx.x * RROWS;
  const int fr  = lane & 15, kg = lane >> 4;
  const int erow = tid >> 5, el = tid & 31;      // elementwise partition: row, lane-in-row

  float c_reg[16];
  // ---- init: h0 -> hsh (swizzled bf16), c0 -> regs ----
  #pragma unroll
  for (int q4=0;q4<4;++q4){
    const int col0 = el*4 + q4*128;
    f4_t hv = *(const f4_t*)&h0[(size_t)(r0+erow)*HID + col0];
    u16x4 hw;
    #pragma unroll
    for (int j=0;j<4;++j) hw[j] = f2bf(hv[j]);
    const int g16 = (col0 >> 3) ^ (erow & 7);
    *(u16x4*)&hsh[erow*512 + (g16<<3) + (col0 & 7)] = hw;
    f4_t cv = *(const f4_t*)&c0[(size_t)(r0+erow)*HID + col0];
    #pragma unroll
    for (int j=0;j<4;++j) c_reg[q4*4+j] = cv[j];
  }
  __syncthreads();

  for (int t=0; t<SEQ; ++t){
    // ---- P1: gatesH = h(16x512) @ Whh^T ; wave w covers gate cols [w*256, w*256+256)
    f4_t acc[16];
    #pragma unroll
    for (int n=0;n<16;++n) acc[n] = (f4_t)0.f;
    #pragma unroll 2
    for (int kt=0; kt<16; ++kt){
      bf8_t af = *(const bf8_t*)&hsh[fr*512 + (((kt*4+kg) ^ (fr&7))*8)];
      #pragma unroll
      for (int n=0;n<16;++n){
        const int col = w*256 + n*16 + fr;
        bf8_t bf_ = *(const bf8_t*)&Whhb[(size_t)col*HID + kt*32 + kg*8];
        acc[n] = __builtin_amdgcn_mfma_f32_16x16x32_bf16(af, bf_, acc[n], 0,0,0);
      }
    }
    // ---- P2: gates -> LDS (f32, swizzled) + per-wave row-stat partials
    float ps[4], ps2[4];
    #pragma unroll
    for (int j=0;j<4;++j){ ps[j]=0.f; ps2[j]=0.f; }
    #pragma unroll
    for (int n=0;n<16;++n){
      const int col = w*256 + n*16 + fr;
      #pragma unroll
      for (int j=0;j<4;++j){
        const int row = kg*4 + j;
        const float v = acc[n][j];
        gates[row*2048 + ((((col>>2) ^ (row&7))<<2) | (col&3))] = v;
        ps[j] += v; ps2[j] += v*v;
      }
    }
    #pragma unroll
    for (int m=1;m<16;m<<=1){
      #pragma unroll
      for (int j=0;j<4;++j){ ps[j]+=__shfl_xor(ps[j],m); ps2[j]+=__shfl_xor(ps2[j],m); }
    }
    if (fr==0){
      #pragma unroll
      for (int j=0;j<4;++j){ part[w][kg*4+j][0]=ps[j]; part[w][kg*4+j][1]=ps2[j]; }
    }
    // ---- P2x: load X spans into regs + X row stats
    u16x4 xq[4][4];
    float sx=0.f, sx2=0.f;
    const unsigned short* xrow = X + ((size_t)(r0+erow)*SEQ + t)*GATE;
    #pragma unroll
    for (int q4=0;q4<4;++q4){
      const int hid0 = el*4 + q4*128;
      #pragma unroll
      for (int qd=0;qd<4;++qd){
        xq[q4][qd] = *(const u16x4*)(xrow + qd*HID + hid0);
        #pragma unroll
        for (int j=0;j<4;++j){ float x = bf2f(xq[q4][qd][j]); sx+=x; sx2+=x*x; }
      }
    }
    #pragma unroll
    for (int m=1;m<32;m<<=1){ sx+=__shfl_xor(sx,m); sx2+=__shfl_xor(sx2,m); }
    if (el==0){
      const float mX = sx*(1.f/GATE);
      stats[erow][2]=mX; stats[erow][3]=rsqrtf(sx2*(1.f/GATE)-mX*mX+EPSV);
    }
    __syncthreads();
    // ---- P3: combine gate-stat partials
    if (tid < RROWS){
      float s=0.f, s2=0.f;
      #pragma unroll
      for (int ww=0;ww<8;++ww){ s+=part[ww][tid][0]; s2+=part[ww][tid][1]; }
      const float mH = s*(1.f/GATE);
      stats[tid][0]=mH; stats[tid][1]=rsqrtf(s2*(1.f/GATE)-mH*mH+EPSV);
    }
    __syncthreads();
    // ---- P4: elementwise LSTM
    const float mH=stats[erow][0], rH=stats[erow][1];
    const float mX=stats[erow][2], rX=stats[erow][3];
    float go_s[16], cs=0.f, cs2=0.f;
    #pragma unroll
    for (int q4=0;q4<4;++q4){
      const int hid0 = el*4 + q4*128;
      const int gswz = (erow&7);
      const f4_t ghi = *(const f4_t*)&gates[erow*2048 + ((((hid0     )>>2) ^ gswz)<<2)];
      const f4_t ghf = *(const f4_t*)&gates[erow*2048 + ((((hid0+ 512)>>2) ^ gswz)<<2)];
      const f4_t ghg = *(const f4_t*)&gates[erow*2048 + ((((hid0+1024)>>2) ^ gswz)<<2)];
      const f4_t gho = *(const f4_t*)&gates[erow*2048 + ((((hid0+1536)>>2) ^ gswz)<<2)];
      const f4_t gi1=*(const f4_t*)&g_ih[hid0],      bi1=*(const f4_t*)&b_ih[hid0];
      const f4_t gi2=*(const f4_t*)&g_ih[hid0+512],  bi2=*(const f4_t*)&b_ih[hid0+512];
      const f4_t gi3=*(const f4_t*)&g_ih[hid0+1024], bi3=*(const f4_t*)&b_ih[hid0+1024];
      const f4_t gi4=*(const f4_t*)&g_ih[hid0+1536], bi4=*(const f4_t*)&b_ih[hid0+1536];
      const f4_t gh1=*(const f4_t*)&g_hh[hid0],      bh1=*(const f4_t*)&b_hh[hid0];
      const f4_t gh2=*(const f4_t*)&g_hh[hid0+512],  bh2=*(const f4_t*)&b_hh[hid0+512];
      const f4_t gh3=*(const f4_t*)&g_hh[hid0+1024], bh3=*(const f4_t*)&b_hh[hid0+1024];
      const f4_t gh4=*(const f4_t*)&g_hh[hid0+1536], bh4=*(const f4_t*)&b_hh[hid0+1536];
      #pragma unroll
      for (int j=0;j<4;++j){
        float gi = (bf2f(xq[q4][0][j])-mX)*rX*gi1[j]+bi1[j] + (ghi[j]-mH)*rH*gh1[j]+bh1[j];
        float gf = (bf2f(xq[q4][1][j])-mX)*rX*gi2[j]+bi2[j] + (ghf[j]-mH)*rH*gh2[j]+bh2[j];
        float gg = (bf2f(xq[q4][2][j])-mX)*rX*gi3[j]+bi3[j] + (ghg[j]-mH)*rH*gh3[j]+bh3[j];
        float go = (bf2f(xq[q4][3][j])-mX)*rX*gi4[j]+bi4[j] + (gho[j]-mH)*rH*gh4[j]+bh4[j];
        const float cn = sigm(gf)*c_reg[q4*4+j] + sigm(gi)*tanh_f(gg);
        c_reg[q4*4+j] = cn; go_s[q4*4+j] = go;
        cs += cn; cs2 += cn*cn;
      }
    }
    #pragma unroll
    for (int m=1;m<32;m<<=1){ cs+=__shfl_xor(cs,m); cs2+=__shfl_xor(cs2,m); }
    const float mC = cs*(1.f/HID);
    const float rC = rsqrtf(cs2*(1.f/HID)-mC*mC+EPSV);
    #pragma unroll
    for (int q4=0;q4<4;++q4){
      const int hid0 = el*4 + q4*128;
      const f4_t gc4=*(const f4_t*)&g_c[hid0], bc4=*(const f4_t*)&b_c[hid0];
      u16x4 hw;
      #pragma unroll
      for (int j=0;j<4;++j){
        float hN = sigm(go_s[q4*4+j])*tanh_f((c_reg[q4*4+j]-mC)*rC*gc4[j]+bc4[j]);
        hw[j] = f2bf(hN);
      }
      const int g16 = (hid0 >> 3) ^ (erow & 7);
      *(u16x4*)&hsh[erow*512 + (g16<<3) + (hid0 & 7)] = hw;
      *(u16x4*)&lo[((size_t)(r0+erow)*SEQ + t)*HID + hid0] = hw;
      if (t==SEQ-1) *(u16x4*)&hb[(size_t)(r0+erow)*HID + hid0] = hw;
    }
    __syncthreads();   // hsh/gates stable for next step's P1/P2
  }
}

// ---------------- fused attention: scores -> softmax -> pooled -> scalar out ----------------
__global__ __launch_bounds__(256) void attn_out_k(
  const float* __restrict__ q, const unsigned short* __restrict__ Km,
  const unsigned short* __restrict__ lo_all,
  const float* __restrict__ u, const float* __restrict__ Cc,
  float* __restrict__ out)
{
  const int b = blockIdx.x, tid = threadIdx.x;
  __shared__ float qs[DK];
  __shared__ float sc[NH][SEQ];
  __shared__ float at[NH][SEQ];
  __shared__ float red[4];
  for (int i=tid; i<DK; i+=256) qs[i] = q[(size_t)b*DK + i];
  __syncthreads();
  {
    const int p = tid>>2, sub = tid&3, h = p>>4, s = p&15;
    const unsigned short* krow = Km + ((size_t)b*SEQ + s)*DK + h*DH + sub*32;
    const float* qh = &qs[h*DH + sub*32];
    float part = 0.f;
    #pragma unroll
    for (int c8=0;c8<4;++c8){
      u16x8 kv = *(const u16x8*)(krow + c8*8);
      #pragma unroll
      for (int j=0;j<8;++j) part += qh[c8*8+j]*bf2f(kv[j]);
    }
    part += __shfl_xor(part,1); part += __shfl_xor(part,2);
    if (sub==0) sc[h][s] = part * 0.08838834764831845f;
  }
  __syncthreads();
  if (tid < 64){
    const int h = tid>>4;
    float v = sc[h][tid&15], mx = v;
    #pragma unroll
    for (int m=1;m<16;m<<=1) mx = fmaxf(mx, __shfl_xor(mx,m));
    float e = __expf(v-mx), se = e;
    #pragma unroll
    for (int m=1;m<16;m<<=1) se += __shfl_xor(se,m);
    at[h][tid&15] = e/se;
  }
  __syncthreads();
  float accum = 0.f;
  #pragma unroll
  for (int it=0; it<4; ++it){
    const int idx = it*256 + tid;
    const int h = idx>>8, d0 = (idx&255)*2;
    const unsigned short* lo = lo_all + (size_t)b*SEQ*HID + d0;
    float p0=0.f, p1=0.f;
    #pragma unroll
    for (int s=0;s<16;++s){
      unsigned int pr = *(const unsigned int*)(lo + s*HID);
      float a = at[h][s];
      p0 += a*bf2f((unsigned short)(pr&0xffffu));
      p1 += a*bf2f((unsigned short)(pr>>16));
    }
    accum += u[h*HID+d0]*p0 + u[h*HID+d0+1]*p1;
  }
  #pragma unroll
  for (int m=32;m;m>>=1) accum += __shfl_xor(accum,m);
  if ((tid&63)==0) red[tid>>6] = accum;
  __syncthreads();
  if (tid==0) out[1+b] = red[0]+red[1]+red[2]+red[3] + Cc[0];
}

__global__ __launch_bounds__(256) void loss_k(const float* __restrict__ label, float* __restrict__ out){
  const int tid = threadIdx.x;
  __shared__ float red[4];
  float s = 0.f;
  for (int b=tid; b<B_SZ; b+=256){
    float d = out[1+b] - label[(size_t)b*SEQ + (SEQ-1)];
    s += d*d;
  }
  #pragma unroll
  for (int m=32;m;m>>=1) s += __shfl_xor(s,m);
  if ((tid&63)==0) red[tid>>6]=s;
  __syncthreads();
  if (tid==0) out[0] = (red[0]+red[1]+red[2]+red[3]) * (1.f/B_SZ);
}

__global__ __launch_bounds__(256) void cvt_bf16_k(const float* __restrict__ in, unsigned short* __restrict__ o, int n){
  int i = (blockIdx.x*256 + threadIdx.x)*4;
  if (i < n){
    f4_t v = *(const f4_t*)&in[i];
    u16x4 w;
    #pragma unroll
    for (int j=0;j<4;++j) w[j] = f2bf(v[j]);
    *(u16x4*)&o[i] = w;
  }
}

// -------- fold wout/out_W/wv into u[h,d] and scalar C (exact: sum(attn)==1) --------
__global__ __launch_bounds__(256) void fold_we_k(
  const float* __restrict__ wout_W, const float* __restrict__ out_W, float* __restrict__ we)
{
  const int j = blockIdx.x*256 + threadIdx.x;
  float s=0.f;
  for (int m=0;m<512;++m) s += out_W[m]*wout_W[(size_t)m*2048+j];
  we[j]=s;
}
__global__ __launch_bounds__(256) void fold_u_k(
  const float* __restrict__ we, const float* __restrict__ wv_W, float* __restrict__ u)
{
  const int o = blockIdx.x*256 + threadIdx.x;
  const int h = o>>9, d = o&511;
  const float* wv = wv_W + (size_t)h*262144 + d;
  const float* wp = we + h*512;
  float s=0.f;
  for (int k=0;k<512;++k) s += wp[k]*wv[(size_t)k*512];
  u[o]=s;
}
__global__ __launch_bounds__(256) void fold_c_k(
  const float* __restrict__ we, const float* __restrict__ wv_b,
  const float* __restrict__ out_W, const float* __restrict__ wout_b,
  const float* __restrict__ out_b, float* __restrict__ Cc)
{
  const int tid = threadIdx.x;
  __shared__ float red[4];
  float s=0.f;
  for (int j=tid;j<2048;j+=256) s += we[j]*wv_b[j];
  for (int m=tid;m<512;m+=256)  s += out_W[m]*wout_b[m];
  #pragma unroll
  for (int m=32;m;m>>=1) s += __shfl_xor(s,m);
  if ((tid&63)==0) red[tid>>6]=s;
  __syncthreads();
  if (tid==0) Cc[0] = red[0]+red[1]+red[2]+red[3] + out_b[0];
}

extern "C" void kernel_launch(void* const* d_in, const int* in_sizes, int n_in,
                              void* d_out, int out_size, void* d_ws, size_t ws_size,
                              hipStream_t stream)
{
  const float* visual = (const float*)d_in[0];
  const float* text   = (const float*)d_in[1];
  const float* user_  = (const float*)d_in[2];
  const float* cat_   = (const float*)d_in[3];
  const float* label  = (const float*)d_in[4];
  const float* h0     = (const float*)d_in[5];
  const float* c0     = (const float*)d_in[6];
  const float* fus_W  = (const float*)d_in[7];
  const float* fus_b  = (const float*)d_in[8];
  const float* W_ih   = (const float*)d_in[9];
  const float* W_hh   = (const float*)d_in[10];
  const float* g_ih   = (const float*)d_in[11];
  const float* b_ih   = (const float*)d_in[12];
  const float* g_hh   = (const float*)d_in[13];
  const float* b_hh   = (const float*)d_in[14];
  const float* g_c    = (const float*)d_in[15];
  const float* b_c    = (const float*)d_in[16];
  const float* wq_W   = (const float*)d_in[17];
  const float* wq_b   = (const float*)d_in[18];
  const float* wk_W   = (const float*)d_in[19];
  const float* wk_b   = (const float*)d_in[20];
  const float* wv_W   = (const float*)d_in[21];
  const float* wv_b   = (const float*)d_in[22];
  const float* wout_W = (const float*)d_in[23];
  const float* wout_b = (const float*)d_in[24];
  const float* out_W  = (const float*)d_in[25];
  const float* out_b  = (const float*)d_in[26];
  (void)in_sizes; (void)n_in; (void)out_size; (void)ws_size;

  char* base = (char*)d_ws; size_t off = 0;
  auto alloc = [&](size_t n)->void*{ void* p = base+off; off += n; off = (off+255)&~(size_t)255; return p; };
  unsigned short* X     = (unsigned short*)alloc((size_t)32768*2048*2);   // 128 MB
  unsigned short* vt    = (unsigned short*)alloc((size_t)32768*1024*2);   // 64 MB
  unsigned short* lo    = (unsigned short*)alloc((size_t)32768*512*2);    // 32 MB
  unsigned short* Km    = (unsigned short*)alloc((size_t)32768*512*2);    // 32 MB
  unsigned short* hb    = (unsigned short*)alloc((size_t)2048*512*2);
  float*          qb    = (float*)         alloc((size_t)2048*512*4);
  unsigned short* fusWb = (unsigned short*)alloc((size_t)1024*4096*2);
  unsigned short* Wihb  = (unsigned short*)alloc((size_t)2048*1024*2);
  unsigned short* Whhb  = (unsigned short*)alloc((size_t)2048*512*2);
  unsigned short* wqb   = (unsigned short*)alloc((size_t)512*512*2);
  unsigned short* wkb   = (unsigned short*)alloc((size_t)512*512*2);
  float*          we_ws = (float*)         alloc(2048*4);
  float*          u_ws  = (float*)         alloc(2048*4);
  float*          C_ws  = (float*)         alloc(256);

  // weight conversions + folds
  cvt_bf16_k<<<dim3(4096), dim3(256), 0, stream>>>(fus_W, fusWb, 1024*4096);
  cvt_bf16_k<<<dim3(2048), dim3(256), 0, stream>>>(W_ih,  Wihb,  2048*1024);
  cvt_bf16_k<<<dim3(1024), dim3(256), 0, stream>>>(W_hh,  Whhb,  2048*512);
  cvt_bf16_k<<<dim3(256),  dim3(256), 0, stream>>>(wq_W,  wqb,   512*512);
  cvt_bf16_k<<<dim3(256),  dim3(256), 0, stream>>>(wk_W,  wkb,   512*512);
  fold_we_k<<<dim3(8), dim3(256), 0, stream>>>(wout_W, out_W, we_ws);
  fold_u_k <<<dim3(8), dim3(256), 0, stream>>>(we_ws, wv_W, u_ws);
  fold_c_k <<<dim3(1), dim3(256), 0, stream>>>(we_ws, wv_b, out_W, wout_b, out_b, C_ws);

  // GEMM1 (fused fp32 A cvt): vt = relu(mods @ fus_W^T + fus_b)  M=32768 N=1024 K=4096
  gemm16f<<<dim3(2048), dim3(256), 0, stream>>>(
      visual, text, user_, cat_, fusWb, fus_b, vt, 1024, 4096, 2048);
  // GEMM2: X = vt @ W_ih^T  (bf16 out; LN renormalizes)  M=32768 N=2048 K=1024
  gemm16<true,false,false><<<dim3(4096), dim3(256), 0, stream>>>(
      vt, Wihb, nullptr, X, 2048, 1024, 4096);

  // full recurrence: ONE launch (batch rows independent)
  rec_fused<<<dim3(128), dim3(512), 0, stream>>>(
      X, Whhb, h0, c0, g_ih, b_ih, g_hh, b_hh, g_c, b_c, lo, hb);

  // q = hn @ wq_W^T + wq_b   (fp32 out)  M=2048 N=512 K=512
  gemm64<false,true><<<dim3(256), dim3(256), 0, stream>>>(
      hb, wqb, wq_b, qb, 512, 512, 256);
  // Kmat = lstm_out @ wk_W^T + wk_b  (bf16 out)  M=32768 N=512 K=512
  gemm16<true,true,false><<<dim3(1024), dim3(256), 0, stream>>>(
      lo, wkb, wk_b, Km, 512, 512, 1024);

  attn_out_k<<<dim3(2048), dim3(256), 0, stream>>>(qb, Km, lo, u_ws, C_ws, (float*)d_out);
  loss_k<<<dim3(1), dim3(256), 0, stream>>>(label, (float*)d_out);
}

// Round 6
// 991.984 us; speedup vs baseline: 2.5918x; 2.5918x over previous
//
#include <hip/hip_runtime.h>
#include <cstdint>

#define B_SZ 2048
#define SEQ  16
#define DIM  1024
#define HID  512
#define DK   512
#define NH   4
#define DH   128
#define GATE 2048
#define EPSV 1e-5f

typedef __bf16 bf8_t __attribute__((ext_vector_type(8)));
typedef float  f4_t  __attribute__((ext_vector_type(4)));
typedef unsigned short u16x8 __attribute__((ext_vector_type(8)));
typedef unsigned short u16x4 __attribute__((ext_vector_type(4)));

__device__ __forceinline__ unsigned short f2bf(float f){
  __bf16 h = (__bf16)f;                       // RNE
  return __builtin_bit_cast(unsigned short, h);
}
__device__ __forceinline__ float bf2f(unsigned short u){
  return __builtin_bit_cast(float, ((unsigned int)u) << 16);
}
__device__ __forceinline__ float sigm(float x){ return 1.f/(1.f+__expf(-x)); }
__device__ __forceinline__ float tanh_f(float x){ return 1.f - 2.f/(__expf(2.f*x)+1.f); }

__device__ __forceinline__ void gload16(const void* g, void* l){
  __builtin_amdgcn_global_load_lds(
      (const __attribute__((address_space(1))) void*)g,
      (__attribute__((address_space(3))) void*)l, 16, 0, 0);
}

// ------------- bf16 BT GEMM 128x128 (m97 structure + granule-XOR swizzle; r3-proven 854 TF) -------------
template<bool OUT_BF16, bool BIAS, bool RELU>
__global__ __launch_bounds__(256) void gemm16(
    const unsigned short* __restrict__ A,
    const unsigned short* __restrict__ Bw,
    const float* __restrict__ bias,
    void* __restrict__ Cp,
    int N, int K, int nwg)
{
  __shared__ __align__(16) unsigned short As[128*64];
  __shared__ __align__(16) unsigned short Bs[128*64];
  const int tid = threadIdx.x, lane = tid & 63, wave = tid >> 6;
  const int bid = blockIdx.x;
  const int swz = (bid & 7)*(nwg >> 3) + (bid >> 3);   // nwg % 8 == 0 at all call sites
  const int nx  = N >> 7;
  const int lnx = 31 - __clz(nx);
  const int bm0 = (swz >> lnx) << 7;
  const int bn0 = (swz & (nx-1)) << 7;

  const int r8  = lane >> 3;
  const int gsw = ((lane & 7) ^ r8) * 8;     // pre-swizzled source granule
  const unsigned short* Ab = A  + (size_t)(bm0 + wave*32 + r8)*K + gsw;
  const unsigned short* Bb = Bw + (size_t)(bn0 + wave*32 + r8)*K + gsw;
  unsigned short* la = As + wave*2048;
  unsigned short* lb = Bs + wave*2048;

  f4_t acc[4][4];
  #pragma unroll
  for (int m=0;m<4;++m)
    #pragma unroll
    for (int n=0;n<4;++n) acc[m][n] = (f4_t)0.f;

  const int KT = K >> 6;
  const int fr = lane & 15, kg = lane >> 4;
  const int wm = (wave & 1)*64, wn = (wave >> 1)*64;

  for (int kt = 0; kt < KT; ++kt){
    if (kt) __syncthreads();
    const size_t ko = (size_t)kt*64;
    #pragma unroll
    for (int q = 0; q < 4; ++q){
      gload16(Ab + ko + (size_t)q*8*K, la + q*512);
      gload16(Bb + ko + (size_t)q*8*K, lb + q*512);
    }
    __syncthreads();
    #pragma unroll
    for (int kk = 0; kk < 2; ++kk){
      bf8_t af[4], bf_[4];
      #pragma unroll
      for (int m=0;m<4;++m){
        const int r = wm+m*16+fr;
        af[m]  = *(const bf8_t*)&As[r*64 + (((kk*4+kg) ^ (r&7))*8)];
      }
      #pragma unroll
      for (int n=0;n<4;++n){
        const int r = wn+n*16+fr;
        bf_[n] = *(const bf8_t*)&Bs[r*64 + (((kk*4+kg) ^ (r&7))*8)];
      }
      #pragma unroll
      for (int m=0;m<4;++m)
        #pragma unroll
        for (int n=0;n<4;++n)
          acc[m][n] = __builtin_amdgcn_mfma_f32_16x16x32_bf16(af[m], bf_[n], acc[m][n], 0,0,0);
    }
  }

  #pragma unroll
  for (int n=0;n<4;++n){
    const int col = bn0 + wn + n*16 + fr;
    float bv = 0.f;
    if constexpr (BIAS) bv = bias[col];
    #pragma unroll
    for (int m=0;m<4;++m){
      #pragma unroll
      for (int j=0;j<4;++j){
        const int row = bm0 + wm + m*16 + kg*4 + j;
        float v = acc[m][n][j] + bv;
        if constexpr (RELU) v = fmaxf(v, 0.f);
        if constexpr (OUT_BF16) ((unsigned short*)Cp)[(size_t)row*N + col] = f2bf(v);
        else                    ((float*)Cp)[(size_t)row*N + col] = v;
      }
    }
  }
}

// ------------- GEMM1 with fused fp32->bf16 A conversion (r5-proven) -------------
__global__ __launch_bounds__(256) void gemm16f(
    const float* __restrict__ A0, const float* __restrict__ A1,
    const float* __restrict__ A2, const float* __restrict__ A3,
    const unsigned short* __restrict__ Bw,
    const float* __restrict__ bias,
    unsigned short* __restrict__ Cp,
    int N, int K, int nwg)
{
  __shared__ __align__(16) unsigned short As[128*64];
  __shared__ __align__(16) unsigned short Bs[128*64];
  const int tid = threadIdx.x, lane = tid & 63, wave = tid >> 6;
  const int bid = blockIdx.x;
  const int swz = (bid & 7)*(nwg >> 3) + (bid >> 3);
  const int nx  = N >> 7;
  const int lnx = 31 - __clz(nx);
  const int bm0 = (swz >> lnx) << 7;
  const int bn0 = (swz & (nx-1)) << 7;

  const int r8  = lane >> 3;
  const int gsw = ((lane & 7) ^ r8) * 8;
  const unsigned short* Bb = Bw + (size_t)(bn0 + wave*32 + r8)*K + gsw;
  unsigned short* lb = Bs + wave*2048;

  const int arow = tid >> 3, acolg = tid & 7;
  f4_t ra[4][2];

  auto loadA = [&](int kt){
    const int kbase = kt*64;
    const int src = kbase >> 10;
    const int kc  = kbase & 1023;
    const float* Asel = src==0?A0 : src==1?A1 : src==2?A2 : A3;
    #pragma unroll
    for (int q=0;q<4;++q){
      const float* p = Asel + (size_t)(bm0 + q*32 + arow)*1024 + kc + acolg*8;
      ra[q][0] = *(const f4_t*)p;
      ra[q][1] = *(const f4_t*)(p+4);
    }
  };
  auto storeA = [&](){
    #pragma unroll
    for (int q=0;q<4;++q){
      const int row = q*32 + arow;
      u16x8 wv;
      #pragma unroll
      for (int j=0;j<4;++j){ wv[j]=f2bf(ra[q][0][j]); wv[4+j]=f2bf(ra[q][1][j]); }
      *(u16x8*)&As[row*64 + ((acolg ^ (row&7))*8)] = wv;
    }
  };

  f4_t acc[4][4];
  #pragma unroll
  for (int m=0;m<4;++m)
    #pragma unroll
    for (int n=0;n<4;++n) acc[m][n] = (f4_t)0.f;

  const int KT = K >> 6;
  const int fr = lane & 15, kg = lane >> 4;
  const int wm = (wave & 1)*64, wn = (wave >> 1)*64;

  loadA(0);
  for (int kt = 0; kt < KT; ++kt){
    if (kt) __builtin_amdgcn_s_barrier();       // all waves done reading LDS tile kt-1
    storeA();                                    // consumes ra (compiler waits their vmcnt)
    const size_t ko = (size_t)kt*64;
    #pragma unroll
    for (int q = 0; q < 4; ++q) gload16(Bb + ko + (size_t)q*8*K, lb + q*512);
    __builtin_amdgcn_sched_barrier(0);           // pin: B gloads issued before A-next loads
    if (kt+1 < KT){
      loadA(kt+1);                               // 8 f32 loads stay in flight across barrier
      __builtin_amdgcn_sched_barrier(0);
      asm volatile("s_waitcnt vmcnt(8)" ::: "memory");   // drains the 4 B gloads (oldest)
    } else {
      asm volatile("s_waitcnt vmcnt(0)" ::: "memory");
    }
    asm volatile("s_waitcnt lgkmcnt(0)" ::: "memory");   // own ds_writes visible
    __builtin_amdgcn_s_barrier();
    __builtin_amdgcn_sched_barrier(0);           // rule-18 fence
    #pragma unroll
    for (int kk = 0; kk < 2; ++kk){
      bf8_t af[4], bf_[4];
      #pragma unroll
      for (int m=0;m<4;++m){
        const int r = wm+m*16+fr;
        af[m]  = *(const bf8_t*)&As[r*64 + (((kk*4+kg) ^ (r&7))*8)];
      }
      #pragma unroll
      for (int n=0;n<4;++n){
        const int r = wn+n*16+fr;
        bf_[n] = *(const bf8_t*)&Bs[r*64 + (((kk*4+kg) ^ (r&7))*8)];
      }
      #pragma unroll
      for (int m=0;m<4;++m)
        #pragma unroll
        for (int n=0;n<4;++n)
          acc[m][n] = __builtin_amdgcn_mfma_f32_16x16x32_bf16(af[m], bf_[n], acc[m][n], 0,0,0);
    }
  }

  #pragma unroll
  for (int n=0;n<4;++n){
    const int col = bn0 + wn + n*16 + fr;
    const float bv = bias[col];
    #pragma unroll
    for (int m=0;m<4;++m){
      #pragma unroll
      for (int j=0;j<4;++j){
        const int row = bm0 + wm + m*16 + kg*4 + j;
        float v = fmaxf(acc[m][n][j] + bv, 0.f);
        Cp[(size_t)row*N + col] = f2bf(v);
      }
    }
  }
}

// ------------- bf16 BT GEMM 64x64 (high-occupancy, for the small recurrent GEMMs; r3-proven) -------------
template<bool OUT_BF16, bool BIAS>
__global__ __launch_bounds__(256) void gemm64(
    const unsigned short* __restrict__ A,
    const unsigned short* __restrict__ Bw,
    const float* __restrict__ bias,
    void* __restrict__ Cp,
    int N, int K, int nwg)
{
  __shared__ __align__(16) unsigned short As[64*64];
  __shared__ __align__(16) unsigned short Bs[64*64];
  const int tid = threadIdx.x, lane = tid & 63, wave = tid >> 6;
  const int bid = blockIdx.x;
  const int swz = (bid & 7)*(nwg >> 3) + (bid >> 3);
  const int nx  = N >> 6;
  const int lnx = 31 - __clz(nx);
  const int bm0 = (swz >> lnx) << 6;
  const int bn0 = (swz & (nx-1)) << 6;

  const int r8  = lane >> 3;
  const int gsw = ((lane & 7) ^ r8) * 8;
  const unsigned short* Ab = A  + (size_t)(bm0 + wave*16 + r8)*K + gsw;
  const unsigned short* Bb = Bw + (size_t)(bn0 + wave*16 + r8)*K + gsw;
  unsigned short* la = As + wave*1024;
  unsigned short* lb = Bs + wave*1024;

  f4_t acc[2][2];
  #pragma unroll
  for (int m=0;m<2;++m)
    #pragma unroll
    for (int n=0;n<2;++n) acc[m][n] = (f4_t)0.f;

  const int KT = K >> 6;
  const int fr = lane & 15, kg = lane >> 4;
  const int wm = (wave & 1)*32, wn = (wave >> 1)*32;

  for (int kt = 0; kt < KT; ++kt){
    if (kt) __syncthreads();
    const size_t ko = (size_t)kt*64;
    #pragma unroll
    for (int q = 0; q < 2; ++q){
      gload16(Ab + ko + (size_t)q*8*K, la + q*512);
      gload16(Bb + ko + (size_t)q*8*K, lb + q*512);
    }
    __syncthreads();
    #pragma unroll
    for (int kk = 0; kk < 2; ++kk){
      bf8_t af[2], bf_[2];
      #pragma unroll
      for (int m=0;m<2;++m){
        const int r = wm+m*16+fr;
        af[m]  = *(const bf8_t*)&As[r*64 + (((kk*4+kg) ^ (r&7))*8)];
      }
      #pragma unroll
      for (int n=0;n<2;++n){
        const int r = wn+n*16+fr;
        bf_[n] = *(const bf8_t*)&Bs[r*64 + (((kk*4+kg) ^ (r&7))*8)];
      }
      #pragma unroll
      for (int m=0;m<2;++m)
        #pragma unroll
        for (int n=0;n<2;++n)
          acc[m][n] = __builtin_amdgcn_mfma_f32_16x16x32_bf16(af[m], bf_[n], acc[m][n], 0,0,0);
    }
  }

  #pragma unroll
  for (int n=0;n<2;++n){
    const int col = bn0 + wn + n*16 + fr;
    float bv = 0.f;
    if constexpr (BIAS) bv = bias[col];
    #pragma unroll
    for (int m=0;m<2;++m){
      #pragma unroll
      for (int j=0;j<4;++j){
        const int row = bm0 + wm + m*16 + kg*4 + j;
        float v = acc[m][n][j] + bv;
        if constexpr (OUT_BF16) ((unsigned short*)Cp)[(size_t)row*N + col] = f2bf(v);
        else                    ((float*)Cp)[(size_t)row*N + col] = v;
      }
    }
  }
}

// ---------------- fused LN + LSTM elementwise step (one WG per batch row; r3-proven) ----------------
__global__ __launch_bounds__(256) void lstm_step(
  const unsigned short* __restrict__ X, const unsigned short* __restrict__ Gh,
  const float* __restrict__ c_src, float* __restrict__ c_dst,
  const float* __restrict__ g_ih, const float* __restrict__ b_ih,
  const float* __restrict__ g_hh, const float* __restrict__ b_hh,
  const float* __restrict__ g_c,  const float* __restrict__ b_c,
  unsigned short* __restrict__ h_out, unsigned short* __restrict__ lstm_out,
  int t)
{
  const int b = blockIdx.x, tid = threadIdx.x;
  __shared__ float xs[GATE];
  __shared__ float gs[GATE];
  __shared__ float red[32];
  const unsigned short* xrow = X  + ((size_t)b*SEQ + t)*GATE;
  const unsigned short* grow = Gh + (size_t)b*GATE;
  u16x8 xv = *(const u16x8*)&xrow[tid*8];
  u16x8 gv = *(const u16x8*)&grow[tid*8];
  float sx=0,sx2=0,sg=0,sg2=0;
  #pragma unroll
  for (int j=0;j<8;++j){
    float x = bf2f(xv[j]), g = bf2f(gv[j]);
    xs[tid*8+j]=x; gs[tid*8+j]=g;
    sx += x; sx2 += x*x; sg += g; sg2 += g*g;
  }
  #pragma unroll
  for (int m=32;m;m>>=1){
    sx += __shfl_xor(sx,m); sx2 += __shfl_xor(sx2,m);
    sg += __shfl_xor(sg,m); sg2 += __shfl_xor(sg2,m);
  }
  const int w = tid>>6;
  if ((tid&63)==0){ red[w]=sx; red[4+w]=sx2; red[8+w]=sg; red[12+w]=sg2; }
  __syncthreads();
  sx  = red[0]+red[1]+red[2]+red[3];
  sx2 = red[4]+red[5]+red[6]+red[7];
  sg  = red[8]+red[9]+red[10]+red[11];
  sg2 = red[12]+red[13]+red[14]+red[15];
  const float mX = sx*(1.f/GATE), mH = sg*(1.f/GATE);
  const float rX = rsqrtf(sx2*(1.f/GATE)-mX*mX+EPSV);
  const float rH = rsqrtf(sg2*(1.f/GATE)-mH*mH+EPSV);

  float cN[2], xo[2]; float sc=0, sc2=0;
  #pragma unroll
  for (int rep=0;rep<2;++rep){
    const int n = tid + rep*256;
    const int ni=n, nf=n+HID, ng=n+2*HID, no=n+3*HID;
    float gi = (xs[ni]-mX)*rX*g_ih[ni]+b_ih[ni] + (gs[ni]-mH)*rH*g_hh[ni]+b_hh[ni];
    float gf = (xs[nf]-mX)*rX*g_ih[nf]+b_ih[nf] + (gs[nf]-mH)*rH*g_hh[nf]+b_hh[nf];
    float gg = (xs[ng]-mX)*rX*g_ih[ng]+b_ih[ng] + (gs[ng]-mH)*rH*g_hh[ng]+b_hh[ng];
    float go = (xs[no]-mX)*rX*g_ih[no]+b_ih[no] + (gs[no]-mH)*rH*g_hh[no]+b_hh[no];
    float co = c_src[(size_t)b*HID + n];
    float cn = sigm(gf)*co + sigm(gi)*tanh_f(gg);
    cN[rep]=cn; xo[rep]=go;
    sc += cn; sc2 += cn*cn;
  }
  #pragma unroll
  for (int m=32;m;m>>=1){ sc += __shfl_xor(sc,m); sc2 += __shfl_xor(sc2,m); }
  if ((tid&63)==0){ red[16+w]=sc; red[20+w]=sc2; }
  __syncthreads();
  sc  = red[16]+red[17]+red[18]+red[19];
  sc2 = red[20]+red[21]+red[22]+red[23];
  const float mC = sc*(1.f/HID);
  const float rC = rsqrtf(sc2*(1.f/HID)-mC*mC+EPSV);
  #pragma unroll
  for (int rep=0;rep<2;++rep){
    const int n = tid + rep*256;
    float hN = sigm(xo[rep])*tanh_f((cN[rep]-mC)*rC*g_c[n]+b_c[n]);
    c_dst[(size_t)b*HID+n] = cN[rep];
    unsigned short hbv = f2bf(hN);
    h_out[(size_t)b*HID+n] = hbv;
    lstm_out[((size_t)b*SEQ+t)*HID+n] = hbv;
  }
}

// ---------------- fused attention: scores -> softmax -> pooled -> scalar out ----------------
__global__ __launch_bounds__(256) void attn_out_k(
  const float* __restrict__ q, const unsigned short* __restrict__ Km,
  const unsigned short* __restrict__ lo_all,
  const float* __restrict__ u, const float* __restrict__ Cc,
  float* __restrict__ out)
{
  const int b = blockIdx.x, tid = threadIdx.x;
  __shared__ float qs[DK];
  __shared__ float sc[NH][SEQ];
  __shared__ float at[NH][SEQ];
  __shared__ float red[4];
  for (int i=tid; i<DK; i+=256) qs[i] = q[(size_t)b*DK + i];
  __syncthreads();
  {
    const int p = tid>>2, sub = tid&3, h = p>>4, s = p&15;
    const unsigned short* krow = Km + ((size_t)b*SEQ + s)*DK + h*DH + sub*32;
    const float* qh = &qs[h*DH + sub*32];
    float part = 0.f;
    #pragma unroll
    for (int c8=0;c8<4;++c8){
      u16x8 kv = *(const u16x8*)(krow + c8*8);
      #pragma unroll
      for (int j=0;j<8;++j) part += qh[c8*8+j]*bf2f(kv[j]);
    }
    part += __shfl_xor(part,1); part += __shfl_xor(part,2);
    if (sub==0) sc[h][s] = part * 0.08838834764831845f;
  }
  __syncthreads();
  if (tid < 64){
    const int h = tid>>4;
    float v = sc[h][tid&15], mx = v;
    #pragma unroll
    for (int m=1;m<16;m<<=1) mx = fmaxf(mx, __shfl_xor(mx,m));
    float e = __expf(v-mx), se = e;
    #pragma unroll
    for (int m=1;m<16;m<<=1) se += __shfl_xor(se,m);
    at[h][tid&15] = e/se;
  }
  __syncthreads();
  float accum = 0.f;
  #pragma unroll
  for (int it=0; it<4; ++it){
    const int idx = it*256 + tid;
    const int h = idx>>8, d0 = (idx&255)*2;
    const unsigned short* lo = lo_all + (size_t)b*SEQ*HID + d0;
    float p0=0.f, p1=0.f;
    #pragma unroll
    for (int s=0;s<16;++s){
      unsigned int pr = *(const unsigned int*)(lo + s*HID);
      float a = at[h][s];
      p0 += a*bf2f((unsigned short)(pr&0xffffu));
      p1 += a*bf2f((unsigned short)(pr>>16));
    }
    accum += u[h*HID+d0]*p0 + u[h*HID+d0+1]*p1;
  }
  #pragma unroll
  for (int m=32;m;m>>=1) accum += __shfl_xor(accum,m);
  if ((tid&63)==0) red[tid>>6] = accum;
  __syncthreads();
  if (tid==0) out[1+b] = red[0]+red[1]+red[2]+red[3] + Cc[0];
}

__global__ __launch_bounds__(256) void loss_k(const float* __restrict__ label, float* __restrict__ out){
  const int tid = threadIdx.x;
  __shared__ float red[4];
  float s = 0.f;
  for (int b=tid; b<B_SZ; b+=256){
    float d = out[1+b] - label[(size_t)b*SEQ + (SEQ-1)];
    s += d*d;
  }
  #pragma unroll
  for (int m=32;m;m>>=1) s += __shfl_xor(s,m);
  if ((tid&63)==0) red[tid>>6]=s;
  __syncthreads();
  if (tid==0) out[0] = (red[0]+red[1]+red[2]+red[3]) * (1.f/B_SZ);
}

__global__ __launch_bounds__(256) void cvt_bf16_k(const float* __restrict__ in, unsigned short* __restrict__ o, int n){
  int i = (blockIdx.x*256 + threadIdx.x)*4;
  if (i < n){
    f4_t v = *(const f4_t*)&in[i];
    u16x4 w;
    #pragma unroll
    for (int j=0;j<4;++j) w[j] = f2bf(v[j]);
    *(u16x4*)&o[i] = w;
  }
}

// -------- fold wout/out_W/wv into u[h,d] and scalar C (exact: sum(attn)==1) --------
__global__ __launch_bounds__(256) void fold_we_k(
  const float* __restrict__ wout_W, const float* __restrict__ out_W, float* __restrict__ we)
{
  const int j = blockIdx.x*256 + threadIdx.x;
  float s=0.f;
  for (int m=0;m<512;++m) s += out_W[m]*wout_W[(size_t)m*2048+j];
  we[j]=s;
}
__global__ __launch_bounds__(256) void fold_u_k(
  const float* __restrict__ we, const float* __restrict__ wv_W, float* __restrict__ u)
{
  const int o = blockIdx.x*256 + threadIdx.x;
  const int h = o>>9, d = o&511;
  const float* wv = wv_W + (size_t)h*262144 + d;
  const float* wp = we + h*512;
  float s=0.f;
  for (int k=0;k<512;++k) s += wp[k]*wv[(size_t)k*512];
  u[o]=s;
}
__global__ __launch_bounds__(256) void fold_c_k(
  const float* __restrict__ we, const float* __restrict__ wv_b,
  const float* __restrict__ out_W, const float* __restrict__ wout_b,
  const float* __restrict__ out_b, float* __restrict__ Cc)
{
  const int tid = threadIdx.x;
  __shared__ float red[4];
  float s=0.f;
  for (int j=tid;j<2048;j+=256) s += we[j]*wv_b[j];
  for (int m=tid;m<512;m+=256)  s += out_W[m]*wout_b[m];
  #pragma unroll
  for (int m=32;m;m>>=1) s += __shfl_xor(s,m);
  if ((tid&63)==0) red[tid>>6]=s;
  __syncthreads();
  if (tid==0) Cc[0] = red[0]+red[1]+red[2]+red[3] + out_b[0];
}

extern "C" void kernel_launch(void* const* d_in, const int* in_sizes, int n_in,
                              void* d_out, int out_size, void* d_ws, size_t ws_size,
                              hipStream_t stream)
{
  const float* visual = (const float*)d_in[0];
  const float* text   = (const float*)d_in[1];
  const float* user_  = (const float*)d_in[2];
  const float* cat_   = (const float*)d_in[3];
  const float* label  = (const float*)d_in[4];
  const float* h0     = (const float*)d_in[5];
  const float* c0     = (const float*)d_in[6];
  const float* fus_W  = (const float*)d_in[7];
  const float* fus_b  = (const float*)d_in[8];
  const float* W_ih   = (const float*)d_in[9];
  const float* W_hh   = (const float*)d_in[10];
  const float* g_ih   = (const float*)d_in[11];
  const float* b_ih   = (const float*)d_in[12];
  const float* g_hh   = (const float*)d_in[13];
  const float* b_hh   = (const float*)d_in[14];
  const float* g_c    = (const float*)d_in[15];
  const float* b_c    = (const float*)d_in[16];
  const float* wq_W   = (const float*)d_in[17];
  const float* wq_b   = (const float*)d_in[18];
  const float* wk_W   = (const float*)d_in[19];
  const float* wk_b   = (const float*)d_in[20];
  const float* wv_W   = (const float*)d_in[21];
  const float* wv_b   = (const float*)d_in[22];
  const float* wout_W = (const float*)d_in[23];
  const float* wout_b = (const float*)d_in[24];
  const float* out_W  = (const float*)d_in[25];
  const float* out_b  = (const float*)d_in[26];
  (void)in_sizes; (void)n_in; (void)out_size; (void)ws_size;

  char* base = (char*)d_ws; size_t off = 0;
  auto alloc = [&](size_t n)->void*{ void* p = base+off; off += n; off = (off+255)&~(size_t)255; return p; };
  unsigned short* X     = (unsigned short*)alloc((size_t)32768*2048*2);   // 128 MB
  unsigned short* vt    = (unsigned short*)alloc((size_t)32768*1024*2);   // 64 MB
  unsigned short* lo    = (unsigned short*)alloc((size_t)32768*512*2);    // 32 MB
  unsigned short* Km    = (unsigned short*)alloc((size_t)32768*512*2);    // 32 MB
  unsigned short* Gh    = (unsigned short*)alloc((size_t)2048*2048*2);    // 8 MB
  float*          cws   = (float*)         alloc((size_t)2048*512*4);     // 4 MB
  unsigned short* hb    = (unsigned short*)alloc((size_t)2048*512*2);
  float*          qb    = (float*)         alloc((size_t)2048*512*4);
  unsigned short* fusWb = (unsigned short*)alloc((size_t)1024*4096*2);
  unsigned short* Wihb  = (unsigned short*)alloc((size_t)2048*1024*2);
  unsigned short* Whhb  = (unsigned short*)alloc((size_t)2048*512*2);
  unsigned short* wqb   = (unsigned short*)alloc((size_t)512*512*2);
  unsigned short* wkb   = (unsigned short*)alloc((size_t)512*512*2);
  float*          we_ws = (float*)         alloc(2048*4);
  float*          u_ws  = (float*)         alloc(2048*4);
  float*          C_ws  = (float*)         alloc(256);

  // weight conversions + folds
  cvt_bf16_k<<<dim3(4096), dim3(256), 0, stream>>>(fus_W, fusWb, 1024*4096);
  cvt_bf16_k<<<dim3(2048), dim3(256), 0, stream>>>(W_ih,  Wihb,  2048*1024);
  cvt_bf16_k<<<dim3(1024), dim3(256), 0, stream>>>(W_hh,  Whhb,  2048*512);
  cvt_bf16_k<<<dim3(256),  dim3(256), 0, stream>>>(wq_W,  wqb,   512*512);
  cvt_bf16_k<<<dim3(256),  dim3(256), 0, stream>>>(wk_W,  wkb,   512*512);
  cvt_bf16_k<<<dim3(1024), dim3(256), 0, stream>>>(h0,    hb,    2048*512);
  fold_we_k<<<dim3(8), dim3(256), 0, stream>>>(wout_W, out_W, we_ws);
  fold_u_k <<<dim3(8), dim3(256), 0, stream>>>(we_ws, wv_W, u_ws);
  fold_c_k <<<dim3(1), dim3(256), 0, stream>>>(we_ws, wv_b, out_W, wout_b, out_b, C_ws);

  // GEMM1 (fused fp32 A cvt): vt = relu(mods @ fus_W^T + fus_b)  M=32768 N=1024 K=4096
  gemm16f<<<dim3(2048), dim3(256), 0, stream>>>(
      visual, text, user_, cat_, fusWb, fus_b, vt, 1024, 4096, 2048);
  // GEMM2: X = vt @ W_ih^T  (bf16 out; LN renormalizes)  M=32768 N=2048 K=1024
  gemm16<true,false,false><<<dim3(4096), dim3(256), 0, stream>>>(
      vt, Wihb, nullptr, X, 2048, 1024, 4096);

  // recurrence (r3-proven: 64x64 tiles -> 1024 WGs, 4/CU)
  for (int t=0; t<SEQ; ++t){
    gemm64<true,false><<<dim3(1024), dim3(256), 0, stream>>>(
        hb, Whhb, nullptr, Gh, 2048, 512, 1024);
    lstm_step<<<dim3(2048), dim3(256), 0, stream>>>(
        X, Gh, (t==0 ? c0 : cws), cws, g_ih, b_ih, g_hh, b_hh, g_c, b_c, hb, lo, t);
  }

  // q = hn @ wq_W^T + wq_b   (fp32 out)  M=2048 N=512 K=512
  gemm64<false,true><<<dim3(256), dim3(256), 0, stream>>>(
      hb, wqb, wq_b, qb, 512, 512, 256);
  // Kmat = lstm_out @ wk_W^T + wk_b  (bf16 out)  M=32768 N=512 K=512
  gemm16<true,true,false><<<dim3(1024), dim3(256), 0, stream>>>(
      lo, wkb, wk_b, Km, 512, 512, 1024);

  attn_out_k<<<dim3(2048), dim3(256), 0, stream>>>(qb, Km, lo, u_ws, C_ws, (float*)d_out);
  loss_k<<<dim3(1), dim3(256), 0, stream>>>(label, (float*)d_out);
}